// Round 1
// baseline (369.194 us; speedup 1.0000x reference)
//
#include <hip/hip_runtime.h>

typedef unsigned short u16;
typedef unsigned int   u32;

#define HID 128

typedef __bf16 bf16x8 __attribute__((ext_vector_type(8)));
typedef float  f32x4  __attribute__((ext_vector_type(4)));

__device__ inline float u2f(u32 u){ union{u32 u;float f;} v; v.u=u; return v.f; }
__device__ inline u32   f2u(float f){ union{float f;u32 u;} v; v.f=f; return v.u; }
// bf16 helpers (round-to-nearest-even pack, exact unpack)
__device__ inline u32  f2bfu(float f){ u32 b=f2u(f); return ((b + 0x7FFFu + ((b>>16)&1u))>>16)&0xFFFFu; }
__device__ inline float blo(u32 u){ return u2f(u<<16); }
__device__ inline float bhi(u32 u){ return u2f(u & 0xFFFF0000u); }

// ---------- fp32 -> bf16 table conversion (vectorized) ----------
__global__ __launch_bounds__(256) void k_f2bf4(const float4* __restrict__ in, ushort4* __restrict__ out, int n4){
    int i = blockIdx.x*256 + threadIdx.x;
    if (i < n4){
        float4 v = in[i];
        ushort4 o;
        o.x = (u16)f2bfu(v.x); o.y = (u16)f2bfu(v.y);
        o.z = (u16)f2bfu(v.z); o.w = (u16)f2bfu(v.w);
        out[i] = o;
    }
}

// ---------- W (128x128 row-major fp32) -> MFMA B-fragment-ordered bf16 ----------
// Wf linear index (((s*8 + j)*64) + lane)*8 + i  holds  W[k][n],
//   k = s*32 + (lane>>4)*8 + i,  n = j*16 + (lane&15)
__global__ __launch_bounds__(256) void k_wfrag(const float* __restrict__ W, u16* __restrict__ Wf){
    int id = blockIdx.x*256 + threadIdx.x;   // 16384 total
    int i = id & 7, l = (id>>3)&63, j = (id>>9)&7, s = id>>12;
    int k = s*32 + ((l>>4)<<3) + i;
    int n = (j<<4) + (l&15);
    Wf[id] = (u16)f2bfu(W[k*HID + n]);
}

// ---------- degree counting ----------
__global__ __launch_bounds__(256) void k_count(const int* __restrict__ nidx, const int* __restrict__ eidx,
                                               int* __restrict__ cnt, int nE, int nN){
    int i = blockIdx.x*256 + threadIdx.x;
    if (i < nE){
        atomicAdd(&cnt[nidx[i]], 1);
        atomicAdd(&cnt[nN + eidx[i]], 1);
    }
}

// ---------- exclusive scan of cnt[0..n) -> off[0..n] (3-kernel, TILE=2048) ----------
__global__ __launch_bounds__(256) void k_scan1(const int* __restrict__ in, int* __restrict__ tsum, int n){
    __shared__ int sd[256];
    int t = threadIdx.x;
    int base = blockIdx.x*2048 + t*8;
    int s = 0;
    #pragma unroll
    for (int k=0;k<8;++k){ int idx = base+k; if (idx < n) s += in[idx]; }
    sd[t] = s; __syncthreads();
    for (int o=128;o>0;o>>=1){ if (t<o) sd[t]+=sd[t+o]; __syncthreads(); }
    if (t==0) tsum[blockIdx.x] = sd[0];
}
__global__ void k_scan2(const int* __restrict__ tsum, int* __restrict__ toff, int nt){
    if (threadIdx.x==0){
        int acc=0;
        for (int i=0;i<nt;++i){ toff[i]=acc; acc+=tsum[i]; }
    }
}
__global__ __launch_bounds__(256) void k_scan3(const int* __restrict__ in, const int* __restrict__ toff,
                                               int* __restrict__ off, int n){
    __shared__ int sd[256];
    int t = threadIdx.x;
    int base = blockIdx.x*2048 + t*8;
    int v[8]; int s=0;
    #pragma unroll
    for (int k=0;k<8;++k){ int idx=base+k; v[k] = (idx<n)? in[idx] : 0; s += v[k]; }
    sd[t]=s; __syncthreads();
    for (int o=1;o<256;o<<=1){
        int x = (t>=o)? sd[t-o] : 0;
        __syncthreads();
        sd[t] += x;
        __syncthreads();
    }
    int ex = sd[t] - s + toff[blockIdx.x];
    #pragma unroll
    for (int k=0;k<8;++k){
        int idx = base+k;
        if (idx < n){
            off[idx] = ex; ex += v[k];
            if (idx == n-1) off[n] = ex;
        }
    }
}

// ---------- CSR scatter: bucket i by node (store edge id) and by edge (store node id) ----------
__global__ __launch_bounds__(256) void k_scatter(const int* __restrict__ nidx, const int* __restrict__ eidx,
                                                 const int* __restrict__ off, int* __restrict__ fill,
                                                 int* __restrict__ csr, int nE, int nN){
    int i = blockIdx.x*256 + threadIdx.x;
    if (i < nE){
        int n = nidx[i], e = eidx[i];
        int p = off[n]      + atomicAdd(&fill[n],      1); csr[p] = e;
        int q = off[nN + e] + atomicAdd(&fill[nN + e], 1); csr[q] = n;
    }
}

// ---------- MFMA GEMM: C[M x 128] = A[M x 128] @ W[128 x 128], bf16 in, bf16 out ----------
// one wave per 16-row strip, all 128 cols; 8 acc tiles of 16x16; K in 4 steps of 32
__global__ __launch_bounds__(256) void k_gemm(const u16* __restrict__ A, const u16* __restrict__ Wf,
                                              u16* __restrict__ C, int M){
    int wave = blockIdx.x*4 + (threadIdx.x>>6);
    int lane = threadIdx.x & 63;
    int rtiles = M >> 4;
    if (wave >= rtiles) return;
    int row0 = wave << 4;

    const u16* Arow = A + (size_t)(row0 + (lane&15))*HID + ((lane>>4)<<3);
    const bf16x8* Wp = reinterpret_cast<const bf16x8*>(Wf) + lane;

    f32x4 acc[8];
    #pragma unroll
    for (int j=0;j<8;++j) acc[j] = (f32x4){0.f,0.f,0.f,0.f};

    #pragma unroll
    for (int s=0;s<4;++s){
        bf16x8 a = *reinterpret_cast<const bf16x8*>(Arow + s*32);
        #pragma unroll
        for (int j=0;j<8;++j){
            bf16x8 b = Wp[(s*8 + j)*64];
            acc[j] = __builtin_amdgcn_mfma_f32_16x16x32_bf16(a, b, acc[j], 0, 0, 0);
        }
    }
    int r0 = row0 + ((lane>>4)<<2);
    int c0 = lane & 15;
    #pragma unroll
    for (int j=0;j<8;++j){
        #pragma unroll
        for (int r=0;r<4;++r){
            C[(size_t)(r0+r)*HID + j*16 + c0] = (u16)f2bfu(acc[j][r]);
        }
    }
}

// ---------- CSR-gather segment mean-sum ----------
// MODE 0: out bf16, scale only                      (node -> hyperedge, * B^-1)
// MODE 1: out bf16, scale + bias + prelu            (hyperedge -> node, * D^-1, layer 1)
// MODE 2: out fp32, scale + bias + residual + prelu (final)
template<int MODE>
__global__ __launch_bounds__(256) void k_agg(const u32* __restrict__ src, const int* __restrict__ csr,
                                             const int* __restrict__ off, void* __restrict__ outp,
                                             const float* __restrict__ bias, const float* __restrict__ resid,
                                             const float* __restrict__ aptr, int nrows){
    int d = blockIdx.x*4 + (threadIdx.x>>6);
    if (d >= nrows) return;
    int lane = threadIdx.x & 63;
    int start = off[d], end = off[d+1];

    float a0 = 0.f, a1 = 0.f;
    int j = start;
    for (; j+4 <= end; j += 4){
        int s0 = csr[j], s1 = csr[j+1], s2 = csr[j+2], s3 = csr[j+3];
        u32 u0 = src[(size_t)s0*64 + lane];
        u32 u1 = src[(size_t)s1*64 + lane];
        u32 u2 = src[(size_t)s2*64 + lane];
        u32 u3 = src[(size_t)s3*64 + lane];
        a0 += blo(u0) + blo(u1) + blo(u2) + blo(u3);
        a1 += bhi(u0) + bhi(u1) + bhi(u2) + bhi(u3);
    }
    for (; j < end; ++j){
        u32 u = src[(size_t)csr[j]*64 + lane];
        a0 += blo(u); a1 += bhi(u);
    }
    float scale = (end > start) ? 1.0f/(float)(end-start) : 0.f;
    a0 *= scale; a1 *= scale;
    if constexpr (MODE >= 1){ a0 += bias[2*lane]; a1 += bias[2*lane+1]; }
    if constexpr (MODE == 2){
        float2 xr = reinterpret_cast<const float2*>(resid)[(size_t)d*64 + lane];
        a0 += xr.x; a1 += xr.y;
    }
    if constexpr (MODE >= 1){
        float al = aptr[0];
        a0 = (a0 >= 0.f) ? a0 : al*a0;
        a1 = (a1 >= 0.f) ? a1 : al*a1;
    }
    if constexpr (MODE == 2){
        reinterpret_cast<float2*>(outp)[(size_t)d*64 + lane] = make_float2(a0, a1);
    } else {
        reinterpret_cast<u32*>(outp)[(size_t)d*64 + lane] = (f2bfu(a1)<<16) | f2bfu(a0);
    }
}

extern "C" void kernel_launch(void* const* d_in, const int* in_sizes, int n_in,
                              void* d_out, int out_size, void* d_ws, size_t ws_size,
                              hipStream_t stream){
    (void)n_in; (void)out_size; (void)ws_size;
    const float* x  = (const float*)d_in[0];
    const int*  hei = (const int*)  d_in[1];
    const float* W1 = (const float*)d_in[2];
    const float* b1 = (const float*)d_in[3];
    const float* W2 = (const float*)d_in[4];
    const float* b2 = (const float*)d_in[5];
    const float* ap = (const float*)d_in[6];

    const int nN = in_sizes[0] / HID;   // 50000
    const int nE = in_sizes[1] / 2;     // 600000
    const int* nidx = hei;
    const int* eidx = hei + nE;

    // workspace layout (256B-aligned slots)
    char* w = (char*)d_ws;
    size_t o = 0;
    auto alloc = [&](size_t bytes)->void*{
        void* p = (void*)(w + o);
        o += (bytes + 255) & ~(size_t)255;
        return p;
    };
    int* cnt  = (int*)alloc((size_t)2*nN*sizeof(int));
    int* fill = (int*)alloc((size_t)2*nN*sizeof(int));
    int* off  = (int*)alloc(((size_t)2*nN+1)*sizeof(int));
    int* tsum = (int*)alloc(64*sizeof(int));
    int* toff = (int*)alloc(64*sizeof(int));
    int* csr  = (int*)alloc((size_t)2*nE*sizeof(int));
    u16* xb   = (u16*)alloc((size_t)nN*HID*sizeof(u16));   // x bf16, later reused as h bf16
    u16* bufB = (u16*)alloc((size_t)nN*HID*sizeof(u16));   // xw / hw
    u16* bufC = (u16*)alloc((size_t)nN*HID*sizeof(u16));   // m / m2
    u16* w1f  = (u16*)alloc((size_t)HID*HID*sizeof(u16));
    u16* w2f  = (u16*)alloc((size_t)HID*HID*sizeof(u16));

    // zero cnt + fill (contiguous span incl. pad)
    size_t zbytes = (size_t)((char*)fill - (char*)cnt) + (size_t)2*nN*sizeof(int);
    hipMemsetAsync(cnt, 0, zbytes, stream);

    const int n4 = nN*HID/4;
    k_f2bf4<<<(n4+255)/256, 256, 0, stream>>>((const float4*)x, (ushort4*)xb, n4);
    k_wfrag<<<64, 256, 0, stream>>>(W1, w1f);
    k_wfrag<<<64, 256, 0, stream>>>(W2, w2f);

    k_count<<<(nE+255)/256, 256, 0, stream>>>(nidx, eidx, cnt, nE, nN);
    const int nkeys = 2*nN;
    const int ntile = (nkeys + 2047)/2048;
    k_scan1<<<ntile, 256, 0, stream>>>(cnt, tsum, nkeys);
    k_scan2<<<1, 64, 0, stream>>>(tsum, toff, ntile);
    k_scan3<<<ntile, 256, 0, stream>>>(cnt, toff, off, nkeys);
    k_scatter<<<(nE+255)/256, 256, 0, stream>>>(nidx, eidx, off, fill, csr, nE, nN);

    const int rtiles = nN/16;
    const int ggrid  = (rtiles + 3)/4;
    const int agrid  = (nN + 3)/4;

    // layer 1
    k_gemm<<<ggrid, 256, 0, stream>>>(xb, w1f, bufB, nN);
    k_agg<0><<<agrid, 256, 0, stream>>>((const u32*)bufB, csr, off + nN, bufC, nullptr, nullptr, nullptr, nN);
    k_agg<1><<<agrid, 256, 0, stream>>>((const u32*)bufC, csr, off,      xb,   b1, nullptr, ap, nN);
    // layer 2
    k_gemm<<<ggrid, 256, 0, stream>>>(xb, w2f, bufB, nN);
    k_agg<0><<<agrid, 256, 0, stream>>>((const u32*)bufB, csr, off + nN, bufC, nullptr, nullptr, nullptr, nN);
    k_agg<2><<<agrid, 256, 0, stream>>>((const u32*)bufC, csr, off, d_out, b2, x, ap, nN);
}

// Round 2
// 281.063 us; speedup vs baseline: 1.3136x; 1.3136x over previous
//
#include <hip/hip_runtime.h>

typedef unsigned short u16;
typedef unsigned int   u32;
typedef unsigned long long u64;

#define HID 128
#define KPB 512      // keys per coarse bucket (shift 9)
#define NBMAX 256    // max coarse buckets (actual: 196)
#define IPB 4096     // incidences per partition workgroup
#define CAP 12288    // LDS val-staging capacity per bucket (mean ~6122, 26-sigma safe)

typedef __bf16 bf16x8 __attribute__((ext_vector_type(8)));
typedef float  f32x4  __attribute__((ext_vector_type(4)));

__device__ inline float u2f(u32 u){ union{u32 u;float f;} v; v.u=u; return v.f; }
__device__ inline u32   f2u(float f){ union{float f;u32 u;} v; v.f=f; return v.u; }
__device__ inline u32  f2bfu(float f){ u32 b=f2u(f); return ((b + 0x7FFFu + ((b>>16)&1u))>>16)&0xFFFFu; }
__device__ inline float blo(u32 u){ return u2f(u<<16); }
__device__ inline float bhi(u32 u){ return u2f(u & 0xFFFF0000u); }

// ---------- fp32 -> bf16 table conversion ----------
__global__ __launch_bounds__(256) void k_f2bf4(const float4* __restrict__ in, ushort4* __restrict__ out, int n4){
    int i = blockIdx.x*256 + threadIdx.x;
    if (i < n4){
        float4 v = in[i];
        ushort4 o;
        o.x = (u16)f2bfu(v.x); o.y = (u16)f2bfu(v.y);
        o.z = (u16)f2bfu(v.z); o.w = (u16)f2bfu(v.w);
        out[i] = o;
    }
}

// ---------- W -> MFMA B-fragment-ordered bf16 ----------
__global__ __launch_bounds__(256) void k_wfrag(const float* __restrict__ W, u16* __restrict__ Wf){
    int id = blockIdx.x*256 + threadIdx.x;   // 16384 total
    int i = id & 7, l = (id>>3)&63, j = (id>>9)&7, s = id>>12;
    int k = s*32 + ((l>>4)<<3) + i;
    int n = (j<<4) + (l&15);
    Wf[id] = (u16)f2bfu(W[k*HID + n]);
}

// ---------- coarse histogram: 196 buckets of 512 keys over combined key space [0, 2*nN) ----------
__global__ __launch_bounds__(256) void k_hist(const int* __restrict__ nidx, const int* __restrict__ eidx,
                                              int* __restrict__ hist, int nE, int nN, int nb){
    __shared__ int h[NBMAX];
    for (int t=threadIdx.x; t<nb; t+=256) h[t]=0;
    __syncthreads();
    int base = blockIdx.x*IPB;
    for (int k=threadIdx.x; k<IPB; k+=256){
        int j = base+k;
        if (j < nE){
            int n = nidx[j], e = eidx[j];
            atomicAdd(&h[n>>9], 1);
            atomicAdd(&h[(nN+e)>>9], 1);
        }
    }
    __syncthreads();
    for (int t=threadIdx.x; t<nb; t+=256) if (h[t]) atomicAdd(&hist[t], h[t]);
}

// ---------- scan of coarse histogram (1 block); seeds bfill; writes off[nkeys] ----------
__global__ __launch_bounds__(256) void k_bscan(const int* __restrict__ hist, int* __restrict__ bbase,
                                               int* __restrict__ bfill, int* __restrict__ off,
                                               int nb, int nkeys, int total){
    __shared__ int sd[256];
    int t = threadIdx.x;
    int v = (t < nb) ? hist[t] : 0;
    sd[t] = v; __syncthreads();
    for (int o=1;o<256;o<<=1){ int u = (t>=o)? sd[t-o] : 0; __syncthreads(); sd[t]+=u; __syncthreads(); }
    int ex = sd[t] - v;
    if (t < nb){ bbase[t] = ex; bfill[t] = ex; }
    if (t == 0){ bbase[nb] = total; off[nkeys] = total; }
}

// ---------- partition into coarse buckets: (key,val) u64 pairs, bucket-contiguous ----------
__global__ __launch_bounds__(256) void k_part(const int* __restrict__ nidx, const int* __restrict__ eidx,
                                              int* __restrict__ bfill, u64* __restrict__ pairs,
                                              int nE, int nN, int nb){
    __shared__ int h[NBMAX], rsv[NBMAX], fl[NBMAX];
    for (int t=threadIdx.x; t<nb; t+=256){ h[t]=0; fl[t]=0; }
    __syncthreads();
    int base = blockIdx.x*IPB;
    for (int k=threadIdx.x; k<IPB; k+=256){
        int j = base+k;
        if (j < nE){
            int n = nidx[j], e = eidx[j];
            atomicAdd(&h[n>>9], 1);
            atomicAdd(&h[(nN+e)>>9], 1);
        }
    }
    __syncthreads();
    for (int t=threadIdx.x; t<nb; t+=256){ if (h[t]) rsv[t] = atomicAdd(&bfill[t], h[t]); }
    __syncthreads();
    for (int k=threadIdx.x; k<IPB; k+=256){
        int j = base+k;
        if (j < nE){
            int n = nidx[j], e = eidx[j];
            int b1 = n>>9;
            int p1 = rsv[b1] + atomicAdd(&fl[b1], 1);
            pairs[p1] = ((u64)(u32)n << 32) | (u32)e;
            int k2 = nN + e;
            int b2 = k2>>9;
            int p2 = rsv[b2] + atomicAdd(&fl[b2], 1);
            pairs[p2] = ((u64)(u32)k2 << 32) | (u32)n;
        }
    }
}

// ---------- per-bucket fine counting sort in LDS: csr (coalesced) + off ----------
__global__ __launch_bounds__(256) void k_bucket(const u64* __restrict__ pairs, const int* __restrict__ bbase,
                                                int* __restrict__ csr, int* __restrict__ off, int nkeys){
    __shared__ int cntS[KPB];
    __shared__ int fillS[KPB];
    __shared__ int sd[256];
    __shared__ int vals[CAP];
    int b = blockIdx.x;
    int t = threadIdx.x;
    int base = bbase[b];
    int n = bbase[b+1] - base;
    int k0 = b * KPB;

    for (int i=t; i<KPB; i+=256) cntS[i] = 0;
    __syncthreads();
    for (int i=t; i<n; i+=256){
        u64 p = pairs[base+i];
        int kl = (int)(p>>32) - k0;
        atomicAdd(&cntS[kl], 1);
    }
    __syncthreads();
    // exclusive scan of cntS[0..512): 2 elems/thread + 256-wide Hillis-Steele
    int c0 = cntS[2*t], c1 = cntS[2*t+1];
    int s = c0 + c1;
    sd[t] = s; __syncthreads();
    for (int o=1;o<256;o<<=1){ int u = (t>=o)? sd[t-o] : 0; __syncthreads(); sd[t]+=u; __syncthreads(); }
    int ex = sd[t] - s;
    __syncthreads();
    cntS[2*t]   = ex;        cntS[2*t+1]   = ex + c0;
    fillS[2*t]  = ex;        fillS[2*t+1]  = ex + c0;
    __syncthreads();
    // write off for this bucket's keys
    for (int i=t; i<KPB; i+=256){
        int k = k0 + i;
        if (k < nkeys) off[k] = base + cntS[i];
    }
    bool fits = (n <= CAP);
    for (int i=t; i<n; i+=256){
        u64 p = pairs[base+i];
        int kl = (int)(p>>32) - k0;
        int pos = atomicAdd(&fillS[kl], 1);
        if (fits) vals[pos] = (int)(u32)p;
        else      csr[base+pos] = (int)(u32)p;   // fallback (statistically unreachable)
    }
    __syncthreads();
    if (fits){
        for (int i=t; i<n; i+=256) csr[base+i] = vals[i];
    }
}

// ---------- MFMA GEMM: C[M x 128] = A[M x 128] @ W[128 x 128], bf16 in/out ----------
__global__ __launch_bounds__(256) void k_gemm(const u16* __restrict__ A, const u16* __restrict__ Wf,
                                              u16* __restrict__ C, int M){
    int wave = blockIdx.x*4 + (threadIdx.x>>6);
    int lane = threadIdx.x & 63;
    int rtiles = M >> 4;
    if (wave >= rtiles) return;
    int row0 = wave << 4;

    const u16* Arow = A + (size_t)(row0 + (lane&15))*HID + ((lane>>4)<<3);
    const bf16x8* Wp = reinterpret_cast<const bf16x8*>(Wf) + lane;

    f32x4 acc[8];
    #pragma unroll
    for (int j=0;j<8;++j) acc[j] = (f32x4){0.f,0.f,0.f,0.f};

    #pragma unroll
    for (int s=0;s<4;++s){
        bf16x8 a = *reinterpret_cast<const bf16x8*>(Arow + s*32);
        #pragma unroll
        for (int j=0;j<8;++j){
            bf16x8 b = Wp[(s*8 + j)*64];
            acc[j] = __builtin_amdgcn_mfma_f32_16x16x32_bf16(a, b, acc[j], 0, 0, 0);
        }
    }
    int r0 = row0 + ((lane>>4)<<2);
    int c0 = lane & 15;
    #pragma unroll
    for (int j=0;j<8;++j){
        #pragma unroll
        for (int r=0;r<4;++r){
            C[(size_t)(r0+r)*HID + j*16 + c0] = (u16)f2bfu(acc[j][r]);
        }
    }
}

// ---------- CSR-gather segment mean ----------
// MODE 0: out bf16, scale only
// MODE 1: out bf16, scale + bias + prelu
// MODE 2: out fp32, scale + bias + residual + prelu
template<int MODE>
__global__ __launch_bounds__(256) void k_agg(const u32* __restrict__ src, const int* __restrict__ csr,
                                             const int* __restrict__ off, void* __restrict__ outp,
                                             const float* __restrict__ bias, const float* __restrict__ resid,
                                             const float* __restrict__ aptr, int nrows){
    int d = blockIdx.x*4 + (threadIdx.x>>6);
    if (d >= nrows) return;
    int lane = threadIdx.x & 63;
    int start = off[d], end = off[d+1];

    float a0 = 0.f, a1 = 0.f;
    int j = start;
    for (; j+4 <= end; j += 4){
        int s0 = csr[j], s1 = csr[j+1], s2 = csr[j+2], s3 = csr[j+3];
        u32 u0 = src[(size_t)s0*64 + lane];
        u32 u1 = src[(size_t)s1*64 + lane];
        u32 u2 = src[(size_t)s2*64 + lane];
        u32 u3 = src[(size_t)s3*64 + lane];
        a0 += blo(u0) + blo(u1) + blo(u2) + blo(u3);
        a1 += bhi(u0) + bhi(u1) + bhi(u2) + bhi(u3);
    }
    for (; j < end; ++j){
        u32 u = src[(size_t)csr[j]*64 + lane];
        a0 += blo(u); a1 += bhi(u);
    }
    float scale = (end > start) ? 1.0f/(float)(end-start) : 0.f;
    a0 *= scale; a1 *= scale;
    if constexpr (MODE >= 1){ a0 += bias[2*lane]; a1 += bias[2*lane+1]; }
    if constexpr (MODE == 2){
        float2 xr = reinterpret_cast<const float2*>(resid)[(size_t)d*64 + lane];
        a0 += xr.x; a1 += xr.y;
    }
    if constexpr (MODE >= 1){
        float al = aptr[0];
        a0 = (a0 >= 0.f) ? a0 : al*a0;
        a1 = (a1 >= 0.f) ? a1 : al*a1;
    }
    if constexpr (MODE == 2){
        reinterpret_cast<float2*>(outp)[(size_t)d*64 + lane] = make_float2(a0, a1);
    } else {
        reinterpret_cast<u32*>(outp)[(size_t)d*64 + lane] = (f2bfu(a1)<<16) | f2bfu(a0);
    }
}

extern "C" void kernel_launch(void* const* d_in, const int* in_sizes, int n_in,
                              void* d_out, int out_size, void* d_ws, size_t ws_size,
                              hipStream_t stream){
    (void)n_in; (void)out_size; (void)ws_size;
    const float* x  = (const float*)d_in[0];
    const int*  hei = (const int*)  d_in[1];
    const float* W1 = (const float*)d_in[2];
    const float* b1 = (const float*)d_in[3];
    const float* W2 = (const float*)d_in[4];
    const float* b2 = (const float*)d_in[5];
    const float* ap = (const float*)d_in[6];

    const int nN = in_sizes[0] / HID;   // 50000
    const int nE = in_sizes[1] / 2;     // 600000
    const int* nidx = hei;
    const int* eidx = hei + nE;
    const int nkeys = 2*nN;
    const int nb    = (nkeys + KPB - 1) / KPB;   // 196

    // workspace layout (256B-aligned slots)
    char* w = (char*)d_ws;
    size_t o = 0;
    auto alloc = [&](size_t bytes)->void*{
        void* p = (void*)(w + o);
        o += (bytes + 255) & ~(size_t)255;
        return p;
    };
    int* hist  = (int*)alloc((size_t)NBMAX*sizeof(int));
    int* bbase = (int*)alloc((size_t)(NBMAX+1)*sizeof(int));
    int* bfill = (int*)alloc((size_t)NBMAX*sizeof(int));
    int* off   = (int*)alloc(((size_t)nkeys+1)*sizeof(int));
    int* csr   = (int*)alloc((size_t)2*nE*sizeof(int));
    u64* pairs = (u64*)alloc((size_t)2*nE*sizeof(u64));
    u16* xb    = (u16*)alloc((size_t)nN*HID*sizeof(u16));   // x bf16, later reused as h bf16
    u16* bufB  = (u16*)alloc((size_t)nN*HID*sizeof(u16));   // xw / hw
    u16* bufC  = (u16*)alloc((size_t)nN*HID*sizeof(u16));   // m / m2
    u16* w1f   = (u16*)alloc((size_t)HID*HID*sizeof(u16));
    u16* w2f   = (u16*)alloc((size_t)HID*HID*sizeof(u16));

    hipMemsetAsync(hist, 0, (size_t)nb*sizeof(int), stream);

    const int n4 = nN*HID/4;
    k_f2bf4<<<(n4+255)/256, 256, 0, stream>>>((const float4*)x, (ushort4*)xb, n4);
    k_wfrag<<<64, 256, 0, stream>>>(W1, w1f);
    k_wfrag<<<64, 256, 0, stream>>>(W2, w2f);

    const int pgrid = (nE + IPB - 1)/IPB;       // 147
    k_hist <<<pgrid, 256, 0, stream>>>(nidx, eidx, hist, nE, nN, nb);
    k_bscan<<<1,     256, 0, stream>>>(hist, bbase, bfill, off, nb, nkeys, 2*nE);
    k_part <<<pgrid, 256, 0, stream>>>(nidx, eidx, bfill, pairs, nE, nN, nb);
    k_bucket<<<nb,   256, 0, stream>>>(pairs, bbase, csr, off, nkeys);

    const int rtiles = nN/16;
    const int ggrid  = (rtiles + 3)/4;
    const int agrid  = (nN + 3)/4;

    // layer 1
    k_gemm<<<ggrid, 256, 0, stream>>>(xb, w1f, bufB, nN);
    k_agg<0><<<agrid, 256, 0, stream>>>((const u32*)bufB, csr, off + nN, bufC, nullptr, nullptr, nullptr, nN);
    k_agg<1><<<agrid, 256, 0, stream>>>((const u32*)bufC, csr, off,      xb,   b1, nullptr, ap, nN);
    // layer 2
    k_gemm<<<ggrid, 256, 0, stream>>>(xb, w2f, bufB, nN);
    k_agg<0><<<agrid, 256, 0, stream>>>((const u32*)bufB, csr, off + nN, bufC, nullptr, nullptr, nullptr, nN);
    k_agg<2><<<agrid, 256, 0, stream>>>((const u32*)bufC, csr, off, d_out, b2, x, ap, nN);
}